// Round 7
// baseline (444.330 us; speedup 1.0000x reference)
//
#include <hip/hip_runtime.h>
#include <hip/hip_bf16.h>

#define D 64
#define N_NODES 50000
#define N_EDGES 800000

// ---------------- CSR build ----------------
__global__ void hist_k(const int* __restrict__ dst, int* __restrict__ cnt, int E) {
    int i = blockIdx.x * blockDim.x + threadIdx.x;
    if (i < E) atomicAdd(&cnt[dst[i]], 1);
}

// per-block scan of cnt -> off (exclusive within block), block sums; also dis = rsqrt(cnt+1)
__global__ void scan1_k(const int* __restrict__ cnt, int* __restrict__ off,
                        int* __restrict__ bsum, float* __restrict__ dis, int N) {
    __shared__ int sh[256];
    int t = threadIdx.x;
    int i = blockIdx.x * 256 + t;
    int v = (i < N) ? cnt[i] : 0;
    sh[t] = v;
    __syncthreads();
#pragma unroll
    for (int d = 1; d < 256; d <<= 1) {
        int u = (t >= d) ? sh[t - d] : 0;
        __syncthreads();
        sh[t] += u;
        __syncthreads();
    }
    if (i < N) {
        off[i] = sh[t] - v;
        dis[i] = rsqrtf((float)v + 1.0f);  // +1 self loop
    }
    if (t == 255) bsum[blockIdx.x] = sh[255];
}

__global__ void scan2_k(int* __restrict__ bsum, int nb) {
    __shared__ int sh[256];
    int t = threadIdx.x;
    int v = (t < nb) ? bsum[t] : 0;
    sh[t] = v;
    __syncthreads();
#pragma unroll
    for (int d = 1; d < 256; d <<= 1) {
        int u = (t >= d) ? sh[t - d] : 0;
        __syncthreads();
        sh[t] += u;
        __syncthreads();
    }
    if (t < nb) bsum[t] = sh[t] - v;
}

__global__ void scan3_k(int* __restrict__ off, const int* __restrict__ bsum,
                        int* __restrict__ cursor, int N, int E) {
    int i = blockIdx.x * 256 + threadIdx.x;
    if (i < N) {
        int o = off[i] + bsum[blockIdx.x];
        off[i] = o;
        cursor[i] = o;
    }
    if (i == 0) off[N] = E;
}

// ---------------- weight transpose: WT[c*64+k] = W[k*64+c] (3 matrices) ----------------
__global__ void transpose_k(const float* __restrict__ W0, const float* __restrict__ W1,
                            const float* __restrict__ W2, float* __restrict__ WT0,
                            float* __restrict__ WT1, float* __restrict__ WT2) {
    const float* Wsrc = (blockIdx.x == 0) ? W0 : (blockIdx.x == 1) ? W1 : W2;
    float* Wdst = (blockIdx.x == 0) ? WT0 : (blockIdx.x == 1) ? WT1 : WT2;
    for (int i = threadIdx.x; i < D * D; i += 256) {
        Wdst[(i & 63) * 64 + (i >> 6)] = Wsrc[i];
    }
}

// ---------------- wave GEMV: out[lane] = h . WT[lane], h distributed as l16 chunks ----------------
// v4 = chunk l16 of the 64-vector (valid in grp 0 at least); WT4 = transposed weights (float4).
// hsh = this wave's 64-float LDS scratch. All DS ops are wave-internal (compiler orders them).
__device__ __forceinline__ float gemv64(float4 v4, const float4* __restrict__ WT4,
                                        float* __restrict__ hsh, int lane, int grp, int l16) {
    if (grp == 0) ((float4*)hsh)[l16] = v4;
    float o = 0.f;
#pragma unroll
    for (int i = 0; i < 16; ++i) {
        float4 hb = ((const float4*)hsh)[i];     // wave-uniform address -> LDS broadcast
        float4 wt = WT4[lane * 16 + i];          // contiguous 16B per lane, L1-resident
        o = fmaf(hb.x, wt.x, o);
        o = fmaf(hb.y, wt.y, o);
        o = fmaf(hb.z, wt.z, o);
        o = fmaf(hb.w, wt.w, o);
    }
    return o;
}

// ---------------- fused: CSR fill (blocks >= gemmBlocks) || gemm0 (blocks < gemmBlocks) ----------------
// gemm0: Hs0[row][c] = (x[row] . WT0[c]) * dis[row], wave per row
__global__ void fused0_k(const float4* __restrict__ X4, const float4* __restrict__ WT0_4,
                         const float* __restrict__ dis, float* __restrict__ H,
                         const int* __restrict__ src, const int* __restrict__ dst,
                         int* __restrict__ cursor, int* __restrict__ esrc,
                         int N, int E, int gemmBlocks) {
    __shared__ float hsh[4][D];
    int bid = blockIdx.x;
    if (bid < gemmBlocks) {
        int w = threadIdx.x >> 6;
        int lane = threadIdx.x & 63;
        int grp = lane >> 4, l16 = lane & 15;
        int gw = bid * 4 + w;
        int nW = gemmBlocks * 4;
        for (int row = gw; row < N; row += nW) {
            float4 v4 = X4[(size_t)row * 16 + l16];
            float o = gemv64(v4, WT0_4, hsh[w], lane, grp, l16);
            H[(size_t)row * 64 + lane] = o * dis[row];
        }
    } else {
        int fb = bid - gemmBlocks;
        int nfb = gridDim.x - gemmBlocks;
        for (int i = fb * 256 + threadIdx.x; i < E; i += nfb * 256) {
            int pos = atomicAdd(&cursor[dst[i]], 1);
            esrc[pos] = src[i];
        }
    }
}

// ---------------- fused layer: gather + activation + next GEMM (or final projection) ----------------
template <int FINAL>
__global__ void layer_k(const float4* __restrict__ Hs4, const int* __restrict__ off,
                        const int* __restrict__ esrc, const float* __restrict__ dis,
                        const float* __restrict__ bias, const float4* __restrict__ WT4,
                        const float* __restrict__ bout, float* __restrict__ outp, int N) {
    __shared__ float hsh[4][D];
    int wid = (blockIdx.x * blockDim.x + threadIdx.x) >> 6;
    int lane = threadIdx.x & 63;
    int grp = lane >> 4;     // edge slot 0..3
    int l16 = lane & 15;     // float4 chunk within row
    if (wid >= N) return;

    int beg = off[wid], end = off[wid + 1];
    float4 acc = make_float4(0.f, 0.f, 0.f, 0.f);
    if (grp == 0) acc = Hs4[(size_t)wid * 16 + l16];  // self-loop term

    int j = beg + grp;
    for (; j + 12 < end; j += 16) {
        int s0 = esrc[j], s1 = esrc[j + 4], s2 = esrc[j + 8], s3 = esrc[j + 12];
        float4 v0 = Hs4[(size_t)s0 * 16 + l16];
        float4 v1 = Hs4[(size_t)s1 * 16 + l16];
        float4 v2 = Hs4[(size_t)s2 * 16 + l16];
        float4 v3 = Hs4[(size_t)s3 * 16 + l16];
        acc.x += (v0.x + v1.x) + (v2.x + v3.x);
        acc.y += (v0.y + v1.y) + (v2.y + v3.y);
        acc.z += (v0.z + v1.z) + (v2.z + v3.z);
        acc.w += (v0.w + v1.w) + (v2.w + v3.w);
    }
    for (; j < end; j += 4) {
        int s = esrc[j];
        float4 v = Hs4[(size_t)s * 16 + l16];
        acc.x += v.x; acc.y += v.y; acc.z += v.z; acc.w += v.w;
    }
#pragma unroll
    for (int m = 16; m <= 32; m <<= 1) {
        acc.x += __shfl_xor(acc.x, m, 64);
        acc.y += __shfl_xor(acc.y, m, 64);
        acc.z += __shfl_xor(acc.z, m, 64);
        acc.w += __shfl_xor(acc.w, m, 64);
    }
    // activation: h = relu(agg * dis[i] + b)
    float dv = dis[wid];
    float4 b4 = ((const float4*)bias)[l16];
    float4 h4;
    h4.x = fmaxf(fmaf(acc.x, dv, b4.x), 0.f);
    h4.y = fmaxf(fmaf(acc.y, dv, b4.y), 0.f);
    h4.z = fmaxf(fmaf(acc.z, dv, b4.z), 0.f);
    h4.w = fmaxf(fmaf(acc.w, dv, b4.w), 0.f);

    if (FINAL) {
        float4 w4 = ((const float4*)WT4)[l16];  // Wout chunk
        float p = fmaf(h4.x, w4.x, fmaf(h4.y, w4.y, fmaf(h4.z, w4.z, h4.w * w4.w)));
        p += __shfl_xor(p, 1, 64);
        p += __shfl_xor(p, 2, 64);
        p += __shfl_xor(p, 4, 64);
        p += __shfl_xor(p, 8, 64);
        if (lane == 0) outp[wid] = p + bout[0];
    } else {
        int w = threadIdx.x >> 6;
        float o = gemv64(h4, WT4, hsh[w], lane, grp, l16);
        outp[(size_t)wid * 64 + lane] = o * dv;  // pre-scale for next layer's gather
    }
}

extern "C" void kernel_launch(void* const* d_in, const int* in_sizes, int n_in,
                              void* d_out, int out_size, void* d_ws, size_t ws_size,
                              hipStream_t stream) {
    const float* x    = (const float*)d_in[0];
    const int*   ei   = (const int*)d_in[1];
    const float* W0   = (const float*)d_in[2];
    const float* b0   = (const float*)d_in[3];
    const float* W1   = (const float*)d_in[4];
    const float* b1   = (const float*)d_in[5];
    const float* W2   = (const float*)d_in[6];
    const float* b2   = (const float*)d_in[7];
    const float* Wout = (const float*)d_in[8];
    const float* bout = (const float*)d_in[9];
    float* out = (float*)d_out;

    const int N = N_NODES, E = N_EDGES;
    const int* src = ei;
    const int* dst = ei + E;

    // ws layout (byte offsets) — verified no overlaps:
    //   cnt    [0,        200000)
    //   off    [262144,   462148)   (N+1 ints)
    //   cursor [524288,   724288)
    //   dis    [786432,   986432)
    //   bsum   [1013760,  1014784)  (990 KiB)
    //   esrc   [1048576,  4248576)  (E ints, ends @4,248,576)
    //   WT0    [4403200,  4419584)  (4300 KiB, 16 KB)
    //   WT1    [4423680,  4440064)  (4320 KiB, 16 KB)
    //   WT2    [4444160,  4460544)  (4340 KiB, 16 KB)
    //   bufA   [5 MiB,    +12.8 MB)
    //   bufB   [18 MiB,   +12.8 MB)
    char* ws = (char*)d_ws;
    int*   cnt    = (int*)(ws);
    int*   off    = (int*)(ws + (256u << 10));
    int*   cursor = (int*)(ws + (512u << 10));
    float* dis    = (float*)(ws + (768u << 10));
    int*   bsum   = (int*)(ws + (990u << 10));
    int*   esrc   = (int*)(ws + (1u << 20));
    float* WT0    = (float*)(ws + (4300u << 10));
    float* WT1    = (float*)(ws + (4320u << 10));
    float* WT2    = (float*)(ws + (4340u << 10));
    float* bufA   = (float*)(ws + (5u << 20));
    float* bufB   = (float*)(ws + (18u << 20));

    dim3 blk(256);
    const int NB = (N + 255) / 256;   // 196
    dim3 gN(NB);
    dim3 gE((E + 255) / 256);         // 3125
    dim3 gWave((N * 64 + 255) / 256); // one wave per node: 12500 blocks
    const int GEMM_BLOCKS = 2048;
    const int FILL_BLOCKS = 1024;

    // ---- degree + CSR offsets + weight transposes ----
    hipMemsetAsync(cnt, 0, (size_t)N * sizeof(int), stream);
    hist_k<<<gE, blk, 0, stream>>>(dst, cnt, E);
    scan1_k<<<gN, blk, 0, stream>>>(cnt, off, bsum, dis, N);
    scan2_k<<<1, blk, 0, stream>>>(bsum, NB);
    scan3_k<<<gN, blk, 0, stream>>>(off, bsum, cursor, N, E);
    transpose_k<<<dim3(3), blk, 0, stream>>>(W0, W1, W2, WT0, WT1, WT2);

    // ---- CSR fill || layer-0 GEMM (independent) ----
    fused0_k<<<dim3(GEMM_BLOCKS + FILL_BLOCKS), blk, 0, stream>>>(
        (const float4*)x, (const float4*)WT0, dis, bufA, src, dst, cursor, esrc,
        N, E, GEMM_BLOCKS);

    // ---- fused layers: gather + relu(bias,dis) + next GEMM ----
    layer_k<0><<<gWave, blk, 0, stream>>>((const float4*)bufA, off, esrc, dis,
                                          b0, (const float4*)WT1, nullptr, bufB, N);
    layer_k<0><<<gWave, blk, 0, stream>>>((const float4*)bufB, off, esrc, dis,
                                          b1, (const float4*)WT2, nullptr, bufA, N);
    // ---- final: gather + relu + projection ----
    layer_k<1><<<gWave, blk, 0, stream>>>((const float4*)bufA, off, esrc, dis,
                                          b2, (const float4*)Wout, bout, out, N);
}

// Round 9
// 322.603 us; speedup vs baseline: 1.3773x; 1.3773x over previous
//
#include <hip/hip_runtime.h>
#include <hip/hip_bf16.h>

#define D 64
#define N_NODES 50000
#define N_EDGES 800000
#define TILE 16   // nodes per block tile (N_NODES % TILE == 0 -> no tails)

// ---------------- CSR build ----------------
__global__ void hist_k(const int* __restrict__ dst, int* __restrict__ cnt, int E) {
    int i = blockIdx.x * blockDim.x + threadIdx.x;
    if (i < E) atomicAdd(&cnt[dst[i]], 1);
}

// per-block scan of cnt -> off (exclusive within block), block sums; also dis = rsqrt(cnt+1)
__global__ void scan1_k(const int* __restrict__ cnt, int* __restrict__ off,
                        int* __restrict__ bsum, float* __restrict__ dis, int N) {
    __shared__ int sh[256];
    int t = threadIdx.x;
    int i = blockIdx.x * 256 + t;
    int v = (i < N) ? cnt[i] : 0;
    sh[t] = v;
    __syncthreads();
#pragma unroll
    for (int d = 1; d < 256; d <<= 1) {
        int u = (t >= d) ? sh[t - d] : 0;
        __syncthreads();
        sh[t] += u;
        __syncthreads();
    }
    if (i < N) {
        off[i] = sh[t] - v;
        dis[i] = rsqrtf((float)v + 1.0f);  // +1 self loop
    }
    if (t == 255) bsum[blockIdx.x] = sh[255];
}

__global__ void scan2_k(int* __restrict__ bsum, int nb) {
    __shared__ int sh[256];
    int t = threadIdx.x;
    int v = (t < nb) ? bsum[t] : 0;
    sh[t] = v;
    __syncthreads();
#pragma unroll
    for (int d = 1; d < 256; d <<= 1) {
        int u = (t >= d) ? sh[t - d] : 0;
        __syncthreads();
        sh[t] += u;
        __syncthreads();
    }
    if (t < nb) bsum[t] = sh[t] - v;
}

__global__ void scan3_k(int* __restrict__ off, const int* __restrict__ bsum,
                        int* __restrict__ cursor, int N, int E) {
    int i = blockIdx.x * 256 + threadIdx.x;
    if (i < N) {
        int o = off[i] + bsum[blockIdx.x];
        off[i] = o;
        cursor[i] = o;
    }
    if (i == 0) off[N] = E;
}

// ---- helper: acc += s * w (componentwise) ----
__device__ __forceinline__ void fma4(float4& a, float s, float4 w) {
    a.x = fmaf(s, w.x, a.x);
    a.y = fmaf(s, w.y, a.y);
    a.z = fmaf(s, w.z, a.z);
    a.w = fmaf(s, w.w, a.w);
}

// ---- Phase B: dense 16x64 tile GEMM out = hbuf @ W, scaled by dis[row].
// thread t: rows rr = (t>>6)*4 + (lane>>4); cols cg*4..cg*4+3 (cg = lane&15).
// W loads fully coalesced (16 consecutive float4 per instr); hbuf reads are
// 4 distinct broadcast addresses in distinct bank groups (68-float row pitch).
__device__ __forceinline__ void tile_gemm(const float (*hbuf)[68], const float4* __restrict__ W4,
                                          const float* __restrict__ dis, float* __restrict__ outp,
                                          int base, int t) {
    int lane = t & 63;
    int cg = lane & 15;
    int rr = (t >> 6) * 4 + (lane >> 4);
    float4 acc = make_float4(0.f, 0.f, 0.f, 0.f);
#pragma unroll
    for (int kk = 0; kk < 16; ++kk) {
        float4 hb = *(const float4*)&hbuf[rr][kk * 4];
        fma4(acc, hb.x, W4[(kk * 4 + 0) * 16 + cg]);
        fma4(acc, hb.y, W4[(kk * 4 + 1) * 16 + cg]);
        fma4(acc, hb.z, W4[(kk * 4 + 2) * 16 + cg]);
        fma4(acc, hb.w, W4[(kk * 4 + 3) * 16 + cg]);
    }
    float dv = dis[base + rr];  // pre-scale for next layer's gather
    acc.x *= dv; acc.y *= dv; acc.z *= dv; acc.w *= dv;
    ((float4*)outp)[(size_t)(base + rr) * 16 + cg] = acc;
}

// ---------------- fused: tile GEMM0 (blocks < gemmBlocks) || CSR fill ----------------
// gemm0: Hs0 = (x @ W0) * dis[row]
__global__ void fused0_k(const float4* __restrict__ X4, const float4* __restrict__ W4,
                         const float* __restrict__ dis, float* __restrict__ H,
                         const int* __restrict__ src, const int* __restrict__ dst,
                         int* __restrict__ cursor, int* __restrict__ esrc,
                         int N, int E, int gemmBlocks) {
    __shared__ float hbuf[TILE][68];
    int bid = blockIdx.x;
    int t = threadIdx.x;
    if (bid < gemmBlocks) {
        int base = bid * TILE;
        // load 16 rows of X, one float4 per thread, coalesced
        int r = t >> 4, ch = t & 15;
        float4 v = X4[(size_t)(base + r) * 16 + ch];
        *(float4*)&hbuf[r][ch * 4] = v;
        __syncthreads();
        tile_gemm(hbuf, W4, dis, H, base, t);
    } else {
        int fb = bid - gemmBlocks;
        int nfb = gridDim.x - gemmBlocks;
        for (int i = fb * 256 + threadIdx.x; i < E; i += nfb * 256) {
            int pos = atomicAdd(&cursor[dst[i]], 1);
            esrc[pos] = src[i];
        }
    }
}

// ---------------- fused layer: group-gather + activation + tile GEMM (or projection) ----------------
// 16 nodes per block. Each 16-lane group gathers one node (lane owns a float4 chunk,
// no cross-lane reduction). Non-final: h tile -> LDS -> dense GEMM with next W.
template <int FINAL>
__global__ void layer_k(const float4* __restrict__ Hs4, const int* __restrict__ off,
                        const int* __restrict__ esrc, const float* __restrict__ dis,
                        const float* __restrict__ bias, const float4* __restrict__ W4,
                        const float* __restrict__ bout, float* __restrict__ outp, int N) {
    __shared__ float hbuf[TILE][68];
    int t = threadIdx.x;
    int lane = t & 63;
    int w = t >> 6;          // wave 0..3
    int g = lane >> 4;       // group 0..3 within wave
    int l16 = lane & 15;     // float4 chunk within row
    int rloc = w * 4 + g;    // local row 0..15
    int n = blockIdx.x * TILE + rloc;

    // ---- gather: acc = Hs[n] + sum_j Hs[esrc[j]] (this lane's 16B chunk) ----
    int beg = off[n], end = off[n + 1];
    float4 acc = Hs4[(size_t)n * 16 + l16];  // self-loop term
    int j = beg;
    for (; j + 3 < end; j += 4) {
        int s0 = esrc[j], s1 = esrc[j + 1], s2 = esrc[j + 2], s3 = esrc[j + 3];
        float4 v0 = Hs4[(size_t)s0 * 16 + l16];
        float4 v1 = Hs4[(size_t)s1 * 16 + l16];
        float4 v2 = Hs4[(size_t)s2 * 16 + l16];
        float4 v3 = Hs4[(size_t)s3 * 16 + l16];
        acc.x += (v0.x + v1.x) + (v2.x + v3.x);
        acc.y += (v0.y + v1.y) + (v2.y + v3.y);
        acc.z += (v0.z + v1.z) + (v2.z + v3.z);
        acc.w += (v0.w + v1.w) + (v2.w + v3.w);
    }
    for (; j < end; ++j) {
        float4 v = Hs4[(size_t)esrc[j] * 16 + l16];
        acc.x += v.x; acc.y += v.y; acc.z += v.z; acc.w += v.w;
    }

    // ---- activation: h = relu(agg * dis[n] + b) ----
    float dv = dis[n];
    float4 b4 = ((const float4*)bias)[l16];
    float4 h4;
    h4.x = fmaxf(fmaf(acc.x, dv, b4.x), 0.f);
    h4.y = fmaxf(fmaf(acc.y, dv, b4.y), 0.f);
    h4.z = fmaxf(fmaf(acc.z, dv, b4.z), 0.f);
    h4.w = fmaxf(fmaf(acc.w, dv, b4.w), 0.f);

    if (FINAL) {
        // out[n] = h . Wout + bout ; reduce within the 16-lane group
        float4 w4 = ((const float4*)W4)[l16];
        float p = fmaf(h4.x, w4.x, fmaf(h4.y, w4.y, fmaf(h4.z, w4.z, h4.w * w4.w)));
        p += __shfl_xor(p, 1, 64);
        p += __shfl_xor(p, 2, 64);
        p += __shfl_xor(p, 4, 64);
        p += __shfl_xor(p, 8, 64);
        if (l16 == 0) outp[n] = p + bout[0];
    } else {
        *(float4*)&hbuf[rloc][l16 * 4] = h4;
        __syncthreads();
        tile_gemm(hbuf, W4, dis, outp, blockIdx.x * TILE, t);
    }
}

extern "C" void kernel_launch(void* const* d_in, const int* in_sizes, int n_in,
                              void* d_out, int out_size, void* d_ws, size_t ws_size,
                              hipStream_t stream) {
    const float* x    = (const float*)d_in[0];
    const int*   ei   = (const int*)d_in[1];
    const float* W0   = (const float*)d_in[2];
    const float* b0   = (const float*)d_in[3];
    const float* W1   = (const float*)d_in[4];
    const float* b1   = (const float*)d_in[5];
    const float* W2   = (const float*)d_in[6];
    const float* b2   = (const float*)d_in[7];
    const float* Wout = (const float*)d_in[8];
    const float* bout = (const float*)d_in[9];
    float* out = (float*)d_out;

    const int N = N_NODES, E = N_EDGES;
    const int* src = ei;
    const int* dst = ei + E;

    // ws layout (byte offsets) — verified no overlaps:
    //   cnt    [0,        200000)
    //   off    [262144,   462148)   (N+1 ints)
    //   cursor [524288,   724288)
    //   dis    [786432,   986432)
    //   bsum   [1013760,  1014784)  (990 KiB)
    //   esrc   [1048576,  4248576)  (E ints)
    //   bufA   [5 MiB,    +12.8 MB)
    //   bufB   [18 MiB,   +12.8 MB)
    char* ws = (char*)d_ws;
    int*   cnt    = (int*)(ws);
    int*   off    = (int*)(ws + (256u << 10));
    int*   cursor = (int*)(ws + (512u << 10));
    float* dis    = (float*)(ws + (768u << 10));
    int*   bsum   = (int*)(ws + (990u << 10));
    int*   esrc   = (int*)(ws + (1u << 20));
    float* bufA   = (float*)(ws + (5u << 20));
    float* bufB   = (float*)(ws + (18u << 20));

    dim3 blk(256);
    const int NB = (N + 255) / 256;      // 196
    dim3 gN(NB);
    dim3 gE((E + 255) / 256);            // 3125
    const int TILES = N / TILE;          // 3125 (exact)
    dim3 gTile(TILES);
    const int FILL_BLOCKS = 1024;

    // ---- degree + CSR offsets ----
    hipMemsetAsync(cnt, 0, (size_t)N * sizeof(int), stream);
    hist_k<<<gE, blk, 0, stream>>>(dst, cnt, E);
    scan1_k<<<gN, blk, 0, stream>>>(cnt, off, bsum, dis, N);
    scan2_k<<<1, blk, 0, stream>>>(bsum, NB);
    scan3_k<<<gN, blk, 0, stream>>>(off, bsum, cursor, N, E);

    // ---- CSR fill || layer-0 GEMM (independent) ----
    fused0_k<<<dim3(TILES + FILL_BLOCKS), blk, 0, stream>>>(
        (const float4*)x, (const float4*)W0, dis, bufA, src, dst, cursor, esrc,
        N, E, TILES);

    // ---- fused layers: gather + relu(bias,dis) + next GEMM ----
    layer_k<0><<<gTile, blk, 0, stream>>>((const float4*)bufA, off, esrc, dis,
                                          b0, (const float4*)W1, nullptr, bufB, N);
    layer_k<0><<<gTile, blk, 0, stream>>>((const float4*)bufB, off, esrc, dis,
                                          b1, (const float4*)W2, nullptr, bufA, N);
    // ---- final: gather + relu + projection ----
    layer_k<1><<<gTile, blk, 0, stream>>>((const float4*)bufA, off, esrc, dis,
                                          b2, (const float4*)Wout, bout, out, N);
}

// Round 10
// 314.553 us; speedup vs baseline: 1.4126x; 1.0256x over previous
//
#include <hip/hip_runtime.h>
#include <hip/hip_bf16.h>

#define D 64
#define N_NODES 50000
#define N_EDGES 800000
#define TILE 16   // nodes per block tile (N_NODES % TILE == 0 -> no tails)

// ---------------- CSR scans ----------------
// per-block scan of cnt -> off (exclusive within block), block sums; also dis = rsqrt(cnt+1)
__global__ void scan1_k(const int* __restrict__ cnt, int* __restrict__ off,
                        int* __restrict__ bsum, float* __restrict__ dis, int N) {
    __shared__ int sh[256];
    int t = threadIdx.x;
    int i = blockIdx.x * 256 + t;
    int v = (i < N) ? cnt[i] : 0;
    sh[t] = v;
    __syncthreads();
#pragma unroll
    for (int d = 1; d < 256; d <<= 1) {
        int u = (t >= d) ? sh[t - d] : 0;
        __syncthreads();
        sh[t] += u;
        __syncthreads();
    }
    if (i < N) {
        off[i] = sh[t] - v;
        dis[i] = rsqrtf((float)v + 1.0f);  // +1 self loop
    }
    if (t == 255) bsum[blockIdx.x] = sh[255];
}

__global__ void scan2_k(int* __restrict__ bsum, int nb) {
    __shared__ int sh[256];
    int t = threadIdx.x;
    int v = (t < nb) ? bsum[t] : 0;
    sh[t] = v;
    __syncthreads();
#pragma unroll
    for (int d = 1; d < 256; d <<= 1) {
        int u = (t >= d) ? sh[t - d] : 0;
        __syncthreads();
        sh[t] += u;
        __syncthreads();
    }
    if (t < nb) bsum[t] = sh[t] - v;
}

__global__ void scan3_k(int* __restrict__ off, const int* __restrict__ bsum,
                        int* __restrict__ cursor, int N, int E) {
    int i = blockIdx.x * 256 + threadIdx.x;
    if (i < N) {
        int o = off[i] + bsum[blockIdx.x];
        off[i] = o;
        cursor[i] = o;
    }
    if (i == 0) off[N] = E;
}

// ---- helper: acc += s * w (componentwise) ----
__device__ __forceinline__ void fma4(float4& a, float s, float4 w) {
    a.x = fmaf(s, w.x, a.x);
    a.y = fmaf(s, w.y, a.y);
    a.z = fmaf(s, w.z, a.z);
    a.w = fmaf(s, w.w, a.w);
}

// ---- dense 16x64 tile GEMM out = hbuf @ W, optionally scaled by dis[row].
// thread t: row rr = (t>>6)*4 + (lane>>4); cols cg*4..cg*4+3 (cg = lane&15).
// W loads fully coalesced (16 consecutive float4/instr); hbuf reads broadcast (68-pitch).
template <int SCALED>
__device__ __forceinline__ void tile_gemm(const float (*hbuf)[68], const float4* __restrict__ W4,
                                          const float* __restrict__ dis, float* __restrict__ outp,
                                          int base, int t) {
    int lane = t & 63;
    int cg = lane & 15;
    int rr = (t >> 6) * 4 + (lane >> 4);
    float4 acc = make_float4(0.f, 0.f, 0.f, 0.f);
#pragma unroll
    for (int kk = 0; kk < 16; ++kk) {
        float4 hb = *(const float4*)&hbuf[rr][kk * 4];
        fma4(acc, hb.x, W4[(kk * 4 + 0) * 16 + cg]);
        fma4(acc, hb.y, W4[(kk * 4 + 1) * 16 + cg]);
        fma4(acc, hb.z, W4[(kk * 4 + 2) * 16 + cg]);
        fma4(acc, hb.w, W4[(kk * 4 + 3) * 16 + cg]);
    }
    if (SCALED) {
        float dv = dis[base + rr];  // pre-scale for next layer's gather
        acc.x *= dv; acc.y *= dv; acc.z *= dv; acc.w *= dv;
    }
    ((float4*)outp)[(size_t)(base + rr) * 16 + cg] = acc;
}

// ---------------- fused prelude: gemm0 UNSCALED (blocks < gemmBlocks) || degree hist ----------------
// gemm0 needs only x,W0 -> runs concurrently with hist (dis not needed yet).
__global__ void fused_pre_k(const float4* __restrict__ X4, const float4* __restrict__ W4,
                            float* __restrict__ H, const int* __restrict__ dst,
                            int* __restrict__ cnt, int N, int E, int gemmBlocks) {
    __shared__ float hbuf[TILE][68];
    int bid = blockIdx.x;
    int t = threadIdx.x;
    if (bid < gemmBlocks) {
        int base = bid * TILE;
        int r = t >> 4, ch = t & 15;
        float4 v = X4[(size_t)(base + r) * 16 + ch];
        *(float4*)&hbuf[r][ch * 4] = v;
        __syncthreads();
        tile_gemm<0>(hbuf, W4, nullptr, H, base, t);
    } else {
        int hb = bid - gemmBlocks;
        int nhb = gridDim.x - gemmBlocks;
        for (int i = hb * 256 + t; i < E; i += nhb * 256) {
            atomicAdd(&cnt[dst[i]], 1);
        }
    }
}

// ---------------- fused: CSR fill (blocks < fillBlocks, 1 edge/thread) || H *= dis[row] ----------------
__global__ void fused_fill_k(const int* __restrict__ src, const int* __restrict__ dst,
                             int* __restrict__ cursor, int* __restrict__ esrc,
                             float4* __restrict__ H4, const float* __restrict__ dis,
                             int N, int E, int fillBlocks) {
    int bid = blockIdx.x;
    int t = threadIdx.x;
    if (bid < fillBlocks) {
        for (int i = bid * 256 + t; i < E; i += fillBlocks * 256) {
            int pos = atomicAdd(&cursor[dst[i]], 1);
            esrc[pos] = src[i];
        }
    } else {
        int sb = bid - fillBlocks;
        int nsb = gridDim.x - fillBlocks;
        int total = N * 16;  // float4 elements
        for (int i = sb * 256 + t; i < total; i += nsb * 256) {
            float4 v = H4[i];
            float dv = dis[i >> 4];
            v.x *= dv; v.y *= dv; v.z *= dv; v.w *= dv;
            H4[i] = v;
        }
    }
}

// ---------------- fused layer: group-gather + activation + tile GEMM (or projection) ----------------
// 16 nodes per block. Each 16-lane group gathers one node (lane owns a float4 chunk).
template <int FINAL>
__global__ void layer_k(const float4* __restrict__ Hs4, const int* __restrict__ off,
                        const int* __restrict__ esrc, const float* __restrict__ dis,
                        const float* __restrict__ bias, const float4* __restrict__ W4,
                        const float* __restrict__ bout, float* __restrict__ outp, int N) {
    __shared__ float hbuf[TILE][68];
    int t = threadIdx.x;
    int lane = t & 63;
    int w = t >> 6;          // wave 0..3
    int g = lane >> 4;       // group 0..3 within wave
    int l16 = lane & 15;     // float4 chunk within row
    int rloc = w * 4 + g;    // local row 0..15
    int n = blockIdx.x * TILE + rloc;

    // ---- gather: acc = Hs[n] + sum_j Hs[esrc[j]] (this lane's 16B chunk), 8-deep unroll ----
    int beg = off[n], end = off[n + 1];
    float4 acc = Hs4[(size_t)n * 16 + l16];  // self-loop term
    int j = beg;
    for (; j + 7 < end; j += 8) {
        int s0 = esrc[j],     s1 = esrc[j + 1], s2 = esrc[j + 2], s3 = esrc[j + 3];
        int s4 = esrc[j + 4], s5 = esrc[j + 5], s6 = esrc[j + 6], s7 = esrc[j + 7];
        float4 v0 = Hs4[(size_t)s0 * 16 + l16];
        float4 v1 = Hs4[(size_t)s1 * 16 + l16];
        float4 v2 = Hs4[(size_t)s2 * 16 + l16];
        float4 v3 = Hs4[(size_t)s3 * 16 + l16];
        float4 v4 = Hs4[(size_t)s4 * 16 + l16];
        float4 v5 = Hs4[(size_t)s5 * 16 + l16];
        float4 v6 = Hs4[(size_t)s6 * 16 + l16];
        float4 v7 = Hs4[(size_t)s7 * 16 + l16];
        acc.x += ((v0.x + v1.x) + (v2.x + v3.x)) + ((v4.x + v5.x) + (v6.x + v7.x));
        acc.y += ((v0.y + v1.y) + (v2.y + v3.y)) + ((v4.y + v5.y) + (v6.y + v7.y));
        acc.z += ((v0.z + v1.z) + (v2.z + v3.z)) + ((v4.z + v5.z) + (v6.z + v7.z));
        acc.w += ((v0.w + v1.w) + (v2.w + v3.w)) + ((v4.w + v5.w) + (v6.w + v7.w));
    }
    for (; j < end; ++j) {
        float4 v = Hs4[(size_t)esrc[j] * 16 + l16];
        acc.x += v.x; acc.y += v.y; acc.z += v.z; acc.w += v.w;
    }

    // ---- activation: h = relu(agg * dis[n] + b) ----
    float dv = dis[n];
    float4 b4 = ((const float4*)bias)[l16];
    float4 h4;
    h4.x = fmaxf(fmaf(acc.x, dv, b4.x), 0.f);
    h4.y = fmaxf(fmaf(acc.y, dv, b4.y), 0.f);
    h4.z = fmaxf(fmaf(acc.z, dv, b4.z), 0.f);
    h4.w = fmaxf(fmaf(acc.w, dv, b4.w), 0.f);

    if (FINAL) {
        // out[n] = h . Wout + bout ; reduce within the 16-lane group
        float4 w4 = ((const float4*)W4)[l16];
        float p = fmaf(h4.x, w4.x, fmaf(h4.y, w4.y, fmaf(h4.z, w4.z, h4.w * w4.w)));
        p += __shfl_xor(p, 1, 64);
        p += __shfl_xor(p, 2, 64);
        p += __shfl_xor(p, 4, 64);
        p += __shfl_xor(p, 8, 64);
        if (l16 == 0) outp[n] = p + bout[0];
    } else {
        *(float4*)&hbuf[rloc][l16 * 4] = h4;
        __syncthreads();
        tile_gemm<1>(hbuf, W4, dis, outp, blockIdx.x * TILE, t);
    }
}

extern "C" void kernel_launch(void* const* d_in, const int* in_sizes, int n_in,
                              void* d_out, int out_size, void* d_ws, size_t ws_size,
                              hipStream_t stream) {
    const float* x    = (const float*)d_in[0];
    const int*   ei   = (const int*)d_in[1];
    const float* W0   = (const float*)d_in[2];
    const float* b0   = (const float*)d_in[3];
    const float* W1   = (const float*)d_in[4];
    const float* b1   = (const float*)d_in[5];
    const float* W2   = (const float*)d_in[6];
    const float* b2   = (const float*)d_in[7];
    const float* Wout = (const float*)d_in[8];
    const float* bout = (const float*)d_in[9];
    float* out = (float*)d_out;

    const int N = N_NODES, E = N_EDGES;
    const int* src = ei;
    const int* dst = ei + E;

    // ws layout (byte offsets) — verified no overlaps:
    //   cnt    [0,        200000)
    //   off    [262144,   462148)   (N+1 ints)
    //   cursor [524288,   724288)
    //   dis    [786432,   986432)
    //   bsum   [1013760,  1014784)  (990 KiB)
    //   esrc   [1048576,  4248576)  (E ints)
    //   bufA   [5 MiB,    +12.8 MB)
    //   bufB   [18 MiB,   +12.8 MB)
    char* ws = (char*)d_ws;
    int*   cnt    = (int*)(ws);
    int*   off    = (int*)(ws + (256u << 10));
    int*   cursor = (int*)(ws + (512u << 10));
    float* dis    = (float*)(ws + (768u << 10));
    int*   bsum   = (int*)(ws + (990u << 10));
    int*   esrc   = (int*)(ws + (1u << 20));
    float* bufA   = (float*)(ws + (5u << 20));
    float* bufB   = (float*)(ws + (18u << 20));

    dim3 blk(256);
    const int NB = (N + 255) / 256;      // 196
    dim3 gN(NB);
    const int TILES = N / TILE;          // 3125 (exact)
    dim3 gTile(TILES);
    const int HIST_BLOCKS = 1563;        // ~2 edges/thread
    const int FILL_BLOCKS = 3125;        // 1 edge/thread (round-5-proven config)
    const int SCALE_BLOCKS = 784;        // H *= dis pass, hides under fill

    // ---- prelude: gemm0 (unscaled) || degree histogram ----
    hipMemsetAsync(cnt, 0, (size_t)N * sizeof(int), stream);
    fused_pre_k<<<dim3(TILES + HIST_BLOCKS), blk, 0, stream>>>(
        (const float4*)x, (const float4*)W0, bufA, dst, cnt, N, E, TILES);

    // ---- CSR offsets (+ dis) ----
    scan1_k<<<gN, blk, 0, stream>>>(cnt, off, bsum, dis, N);
    scan2_k<<<1, blk, 0, stream>>>(bsum, NB);
    scan3_k<<<gN, blk, 0, stream>>>(off, bsum, cursor, N, E);

    // ---- CSR fill || H *= dis[row] ----
    fused_fill_k<<<dim3(FILL_BLOCKS + SCALE_BLOCKS), blk, 0, stream>>>(
        src, dst, cursor, esrc, (float4*)bufA, dis, N, E, FILL_BLOCKS);

    // ---- fused layers: gather + relu(bias,dis) + next GEMM ----
    layer_k<0><<<gTile, blk, 0, stream>>>((const float4*)bufA, off, esrc, dis,
                                          b0, (const float4*)W1, nullptr, bufB, N);
    layer_k<0><<<gTile, blk, 0, stream>>>((const float4*)bufB, off, esrc, dis,
                                          b1, (const float4*)W2, nullptr, bufA, N);
    // ---- final: gather + relu + projection ----
    layer_k<1><<<gTile, blk, 0, stream>>>((const float4*)bufA, off, esrc, dis,
                                          b2, (const float4*)Wout, bout, out, N);
}

// Round 11
// 307.382 us; speedup vs baseline: 1.4455x; 1.0233x over previous
//
#include <hip/hip_runtime.h>
#include <hip/hip_bf16.h>

#define D 64
#define N_NODES 50000
#define N_EDGES 800000
#define TILE 16   // nodes per block tile (N_NODES % TILE == 0 -> no tails)

// ---------------- degree histogram (standalone: atomics-only kernel) ----------------
__global__ void hist_k(const int* __restrict__ dst, int* __restrict__ cnt, int E) {
    int i = blockIdx.x * blockDim.x + threadIdx.x;
    if (i < E) atomicAdd(&cnt[dst[i]], 1);
}

// ---------------- CSR scans ----------------
__global__ void scan1_k(const int* __restrict__ cnt, int* __restrict__ off,
                        int* __restrict__ bsum, float* __restrict__ dis, int N) {
    __shared__ int sh[256];
    int t = threadIdx.x;
    int i = blockIdx.x * 256 + t;
    int v = (i < N) ? cnt[i] : 0;
    sh[t] = v;
    __syncthreads();
#pragma unroll
    for (int d = 1; d < 256; d <<= 1) {
        int u = (t >= d) ? sh[t - d] : 0;
        __syncthreads();
        sh[t] += u;
        __syncthreads();
    }
    if (i < N) {
        off[i] = sh[t] - v;
        dis[i] = rsqrtf((float)v + 1.0f);  // +1 self loop
    }
    if (t == 255) bsum[blockIdx.x] = sh[255];
}

__global__ void scan2_k(int* __restrict__ bsum, int nb) {
    __shared__ int sh[256];
    int t = threadIdx.x;
    int v = (t < nb) ? bsum[t] : 0;
    sh[t] = v;
    __syncthreads();
#pragma unroll
    for (int d = 1; d < 256; d <<= 1) {
        int u = (t >= d) ? sh[t - d] : 0;
        __syncthreads();
        sh[t] += u;
        __syncthreads();
    }
    if (t < nb) bsum[t] = sh[t] - v;
}

__global__ void scan3_k(int* __restrict__ off, const int* __restrict__ bsum,
                        int* __restrict__ cursor, int N, int E) {
    int i = blockIdx.x * 256 + threadIdx.x;
    if (i < N) {
        int o = off[i] + bsum[blockIdx.x];
        off[i] = o;
        cursor[i] = o;
    }
    if (i == 0) off[N] = E;
}

// ---- helper: acc += s * w (componentwise) ----
__device__ __forceinline__ void fma4(float4& a, float s, float4 w) {
    a.x = fmaf(s, w.x, a.x);
    a.y = fmaf(s, w.y, a.y);
    a.z = fmaf(s, w.z, a.z);
    a.w = fmaf(s, w.w, a.w);
}

// ---- dense 16x64 tile GEMM out = hbuf @ W, optionally scaled by dis[row].
template <int SCALED>
__device__ __forceinline__ void tile_gemm(const float (*hbuf)[68], const float4* __restrict__ W4,
                                          const float* __restrict__ dis, float* __restrict__ outp,
                                          int base, int t) {
    int lane = t & 63;
    int cg = lane & 15;
    int rr = (t >> 6) * 4 + (lane >> 4);
    float4 acc = make_float4(0.f, 0.f, 0.f, 0.f);
#pragma unroll
    for (int kk = 0; kk < 16; ++kk) {
        float4 hb = *(const float4*)&hbuf[rr][kk * 4];
        fma4(acc, hb.x, W4[(kk * 4 + 0) * 16 + cg]);
        fma4(acc, hb.y, W4[(kk * 4 + 1) * 16 + cg]);
        fma4(acc, hb.z, W4[(kk * 4 + 2) * 16 + cg]);
        fma4(acc, hb.w, W4[(kk * 4 + 3) * 16 + cg]);
    }
    if (SCALED) {
        float dv = dis[base + rr];
        acc.x *= dv; acc.y *= dv; acc.z *= dv; acc.w *= dv;
    }
    ((float4*)outp)[(size_t)(base + rr) * 16 + cg] = acc;
}

// ---------------- standalone gemm0: H = x @ W0 (unscaled; scale fused into fill pass) ----------------
__global__ void gemm0_k(const float4* __restrict__ X4, const float4* __restrict__ W4,
                        float* __restrict__ H, int N) {
    __shared__ float hbuf[TILE][68];
    int t = threadIdx.x;
    int base = blockIdx.x * TILE;
    int r = t >> 4, ch = t & 15;
    float4 v = X4[(size_t)(base + r) * 16 + ch];
    *(float4*)&hbuf[r][ch * 4] = v;
    __syncthreads();
    tile_gemm<0>(hbuf, W4, nullptr, H, base, t);
}

// ---------------- fused: CSR fill (blocks < fillBlocks, 1 edge/thread) || H *= dis[row] ----------------
__global__ void fused_fill_k(const int* __restrict__ src, const int* __restrict__ dst,
                             int* __restrict__ cursor, int* __restrict__ esrc,
                             float4* __restrict__ H4, const float* __restrict__ dis,
                             int N, int E, int fillBlocks) {
    int bid = blockIdx.x;
    int t = threadIdx.x;
    if (bid < fillBlocks) {
        for (int i = bid * 256 + t; i < E; i += fillBlocks * 256) {
            int pos = atomicAdd(&cursor[dst[i]], 1);
            esrc[pos] = src[i];
        }
    } else {
        int sb = bid - fillBlocks;
        int nsb = gridDim.x - fillBlocks;
        int total = N * 16;  // float4 elements
        for (int i = sb * 256 + t; i < total; i += nsb * 256) {
            float4 v = H4[i];
            float dv = dis[i >> 4];
            v.x *= dv; v.y *= dv; v.z *= dv; v.w *= dv;
            H4[i] = v;
        }
    }
}

// ---------------- fused layer: group-gather + activation + tile GEMM (or projection) ----------------
// 16 nodes per block; each 16-lane group gathers one node (lane owns a float4 chunk).
// Gather issues loads in batches of 8 ALWAYS: full batches unconditional, tail batch
// predicated (clamped index + 0/1-mask FMA) so no serial dependent-load remainder.
template <int FINAL>
__global__ void layer_k(const float4* __restrict__ Hs4, const int* __restrict__ off,
                        const int* __restrict__ esrc, const float* __restrict__ dis,
                        const float* __restrict__ bias, const float4* __restrict__ W4,
                        const float* __restrict__ bout, float* __restrict__ outp, int N) {
    __shared__ float hbuf[TILE][68];
    int t = threadIdx.x;
    int lane = t & 63;
    int w = t >> 6;
    int g = lane >> 4;
    int l16 = lane & 15;
    int rloc = w * 4 + g;
    int n = blockIdx.x * TILE + rloc;

    int beg = off[n], end = off[n + 1];
    float4 acc = Hs4[(size_t)n * 16 + l16];  // self-loop term
    int j = beg;
    // full batches of 8 (unconditional)
    for (; j + 8 <= end; j += 8) {
        int s0 = esrc[j],     s1 = esrc[j + 1], s2 = esrc[j + 2], s3 = esrc[j + 3];
        int s4 = esrc[j + 4], s5 = esrc[j + 5], s6 = esrc[j + 6], s7 = esrc[j + 7];
        float4 v0 = Hs4[(size_t)s0 * 16 + l16];
        float4 v1 = Hs4[(size_t)s1 * 16 + l16];
        float4 v2 = Hs4[(size_t)s2 * 16 + l16];
        float4 v3 = Hs4[(size_t)s3 * 16 + l16];
        float4 v4 = Hs4[(size_t)s4 * 16 + l16];
        float4 v5 = Hs4[(size_t)s5 * 16 + l16];
        float4 v6 = Hs4[(size_t)s6 * 16 + l16];
        float4 v7 = Hs4[(size_t)s7 * 16 + l16];
        acc.x += ((v0.x + v1.x) + (v2.x + v3.x)) + ((v4.x + v5.x) + (v6.x + v7.x));
        acc.y += ((v0.y + v1.y) + (v2.y + v3.y)) + ((v4.y + v5.y) + (v6.y + v7.y));
        acc.z += ((v0.z + v1.z) + (v2.z + v3.z)) + ((v4.z + v5.z) + (v6.z + v7.z));
        acc.w += ((v0.w + v1.w) + (v2.w + v3.w)) + ((v4.w + v5.w) + (v6.w + v7.w));
    }
    // predicated tail batch (0..7 real edges, all loads issued concurrently)
    if (j < end) {
        int last = end - 1;
        int i1 = j + 1 <= last ? j + 1 : last;
        int i2 = j + 2 <= last ? j + 2 : last;
        int i3 = j + 3 <= last ? j + 3 : last;
        int i4 = j + 4 <= last ? j + 4 : last;
        int i5 = j + 5 <= last ? j + 5 : last;
        int i6 = j + 6 <= last ? j + 6 : last;
        int i7 = j + 7 <= last ? j + 7 : last;
        int s0 = esrc[j],  s1 = esrc[i1], s2 = esrc[i2], s3 = esrc[i3];
        int s4 = esrc[i4], s5 = esrc[i5], s6 = esrc[i6], s7 = esrc[i7];
        float m1 = (j + 1 < end) ? 1.f : 0.f;
        float m2 = (j + 2 < end) ? 1.f : 0.f;
        float m3 = (j + 3 < end) ? 1.f : 0.f;
        float m4 = (j + 4 < end) ? 1.f : 0.f;
        float m5 = (j + 5 < end) ? 1.f : 0.f;
        float m6 = (j + 6 < end) ? 1.f : 0.f;
        float m7 = (j + 7 < end) ? 1.f : 0.f;
        float4 v0 = Hs4[(size_t)s0 * 16 + l16];
        float4 v1 = Hs4[(size_t)s1 * 16 + l16];
        float4 v2 = Hs4[(size_t)s2 * 16 + l16];
        float4 v3 = Hs4[(size_t)s3 * 16 + l16];
        float4 v4 = Hs4[(size_t)s4 * 16 + l16];
        float4 v5 = Hs4[(size_t)s5 * 16 + l16];
        float4 v6 = Hs4[(size_t)s6 * 16 + l16];
        float4 v7 = Hs4[(size_t)s7 * 16 + l16];
        acc.x += v0.x;           acc.y += v0.y;           acc.z += v0.z;           acc.w += v0.w;
        acc.x = fmaf(m1, v1.x, acc.x); acc.y = fmaf(m1, v1.y, acc.y); acc.z = fmaf(m1, v1.z, acc.z); acc.w = fmaf(m1, v1.w, acc.w);
        acc.x = fmaf(m2, v2.x, acc.x); acc.y = fmaf(m2, v2.y, acc.y); acc.z = fmaf(m2, v2.z, acc.z); acc.w = fmaf(m2, v2.w, acc.w);
        acc.x = fmaf(m3, v3.x, acc.x); acc.y = fmaf(m3, v3.y, acc.y); acc.z = fmaf(m3, v3.z, acc.z); acc.w = fmaf(m3, v3.w, acc.w);
        acc.x = fmaf(m4, v4.x, acc.x); acc.y = fmaf(m4, v4.y, acc.y); acc.z = fmaf(m4, v4.z, acc.z); acc.w = fmaf(m4, v4.w, acc.w);
        acc.x = fmaf(m5, v5.x, acc.x); acc.y = fmaf(m5, v5.y, acc.y); acc.z = fmaf(m5, v5.z, acc.z); acc.w = fmaf(m5, v5.w, acc.w);
        acc.x = fmaf(m6, v6.x, acc.x); acc.y = fmaf(m6, v6.y, acc.y); acc.z = fmaf(m6, v6.z, acc.z); acc.w = fmaf(m6, v6.w, acc.w);
        acc.x = fmaf(m7, v7.x, acc.x); acc.y = fmaf(m7, v7.y, acc.y); acc.z = fmaf(m7, v7.z, acc.z); acc.w = fmaf(m7, v7.w, acc.w);
    }

    // ---- activation: h = relu(agg * dis[n] + b) ----
    float dv = dis[n];
    float4 b4 = ((const float4*)bias)[l16];
    float4 h4;
    h4.x = fmaxf(fmaf(acc.x, dv, b4.x), 0.f);
    h4.y = fmaxf(fmaf(acc.y, dv, b4.y), 0.f);
    h4.z = fmaxf(fmaf(acc.z, dv, b4.z), 0.f);
    h4.w = fmaxf(fmaf(acc.w, dv, b4.w), 0.f);

    if (FINAL) {
        float4 w4 = ((const float4*)W4)[l16];
        float p = fmaf(h4.x, w4.x, fmaf(h4.y, w4.y, fmaf(h4.z, w4.z, h4.w * w4.w)));
        p += __shfl_xor(p, 1, 64);
        p += __shfl_xor(p, 2, 64);
        p += __shfl_xor(p, 4, 64);
        p += __shfl_xor(p, 8, 64);
        if (l16 == 0) outp[n] = p + bout[0];
    } else {
        *(float4*)&hbuf[rloc][l16 * 4] = h4;
        __syncthreads();
        tile_gemm<1>(hbuf, W4, dis, outp, blockIdx.x * TILE, t);
    }
}

extern "C" void kernel_launch(void* const* d_in, const int* in_sizes, int n_in,
                              void* d_out, int out_size, void* d_ws, size_t ws_size,
                              hipStream_t stream) {
    const float* x    = (const float*)d_in[0];
    const int*   ei   = (const int*)d_in[1];
    const float* W0   = (const float*)d_in[2];
    const float* b0   = (const float*)d_in[3];
    const float* W1   = (const float*)d_in[4];
    const float* b1   = (const float*)d_in[5];
    const float* W2   = (const float*)d_in[6];
    const float* b2   = (const float*)d_in[7];
    const float* Wout = (const float*)d_in[8];
    const float* bout = (const float*)d_in[9];
    float* out = (float*)d_out;

    const int N = N_NODES, E = N_EDGES;
    const int* src = ei;
    const int* dst = ei + E;

    // ws layout (byte offsets) — verified no overlaps:
    //   cnt    [0,        200000)
    //   off    [262144,   462148)   (N+1 ints)
    //   cursor [524288,   724288)
    //   dis    [786432,   986432)
    //   bsum   [1013760,  1014784)  (990 KiB)
    //   esrc   [1048576,  4248576)  (E ints)
    //   bufA   [5 MiB,    +12.8 MB)
    //   bufB   [18 MiB,   +12.8 MB)
    char* ws = (char*)d_ws;
    int*   cnt    = (int*)(ws);
    int*   off    = (int*)(ws + (256u << 10));
    int*   cursor = (int*)(ws + (512u << 10));
    float* dis    = (float*)(ws + (768u << 10));
    int*   bsum   = (int*)(ws + (990u << 10));
    int*   esrc   = (int*)(ws + (1u << 20));
    float* bufA   = (float*)(ws + (5u << 20));
    float* bufB   = (float*)(ws + (18u << 20));

    dim3 blk(256);
    const int NB = (N + 255) / 256;      // 196
    dim3 gN(NB);
    dim3 gE((E + 255) / 256);            // 3125 (1 edge/thread)
    const int TILES = N / TILE;          // 3125 (exact)
    dim3 gTile(TILES);
    const int FILL_BLOCKS = 3125;        // 1 edge/thread (round-5-proven)
    const int SCALE_BLOCKS = 784;

    // ---- prelude (DE-FUSED: atomic kernels separate from streaming kernels) ----
    hipMemsetAsync(cnt, 0, (size_t)N * sizeof(int), stream);
    hist_k<<<gE, blk, 0, stream>>>(dst, cnt, E);
    gemm0_k<<<gTile, blk, 0, stream>>>((const float4*)x, (const float4*)W0, bufA, N);

    // ---- CSR offsets (+ dis) ----
    scan1_k<<<gN, blk, 0, stream>>>(cnt, off, bsum, dis, N);
    scan2_k<<<1, blk, 0, stream>>>(bsum, NB);
    scan3_k<<<gN, blk, 0, stream>>>(off, bsum, cursor, N, E);

    // ---- CSR fill || H *= dis[row] ----
    fused_fill_k<<<dim3(FILL_BLOCKS + SCALE_BLOCKS), blk, 0, stream>>>(
        src, dst, cursor, esrc, (float4*)bufA, dis, N, E, FILL_BLOCKS);

    // ---- fused layers: gather + relu(bias,dis) + next GEMM ----
    layer_k<0><<<gTile, blk, 0, stream>>>((const float4*)bufA, off, esrc, dis,
                                          b0, (const float4*)W1, nullptr, bufB, N);
    layer_k<0><<<gTile, blk, 0, stream>>>((const float4*)bufB, off, esrc, dis,
                                          b1, (const float4*)W2, nullptr, bufA, N);
    // ---- final: gather + relu + projection ----
    layer_k<1><<<gTile, blk, 0, stream>>>((const float4*)bufA, off, esrc, dis,
                                          b2, (const float4*)Wout, bout, out, N);
}